// Round 1
// baseline (1916.023 us; speedup 1.0000x reference)
//
#include <hip/hip_runtime.h>
#include <math.h>
#include <float.h>

#define EPSV 1e-8f
#define MASK_FILL 1000000000.0f
constexpr int D = 64;

// ---------------------------------------------------------------------------
// Kernel 1: normalize codebook rows.
//   cb   = codebook / (||codebook|| + eps)          (natural [K][64] layout)
//   cb_n = cb / (||cb|| + eps)                      (normalized twice, stored
//          tile-transposed: per 64-row tile, [16 float4-groups][64 codes])
// ---------------------------------------------------------------------------
__global__ __launch_bounds__(256) void k_cb(const float* __restrict__ cbin,
                                            float* __restrict__ cb,
                                            float4* __restrict__ cbt) {
    __shared__ float tile[16 * 64 * 4];  // [g][c][4] = 16 KB
    const int t = threadIdx.x;
    const int wv = t >> 6, lane = t & 63;
    const int tileRow0 = blockIdx.x * 64;

    for (int j = 0; j < 16; ++j) {
        const int c = wv * 16 + j;            // code within tile
        const int row = tileRow0 + c;
        float v = cbin[row * D + lane];
        float ss = v * v;
        #pragma unroll
        for (int off = 32; off; off >>= 1) ss += __shfl_xor(ss, off, 64);
        const float n1 = sqrtf(ss);
        const float c1 = v / (n1 + EPSV);
        cb[row * D + lane] = c1;
        float ss2 = c1 * c1;
        #pragma unroll
        for (int off = 32; off; off >>= 1) ss2 += __shfl_xor(ss2, off, 64);
        const float n2 = sqrtf(ss2);
        const float c2 = c1 / (n2 + EPSV);
        // transposed store: float offset (d/4)*256 + c*4 + (d%4)
        tile[(lane >> 2) * 256 + c * 4 + (lane & 3)] = c2;
    }
    __syncthreads();
    float4* dst = cbt + (size_t)blockIdx.x * 1024;
    const float4* srcT = (const float4*)tile;
    #pragma unroll
    for (int i = 0; i < 4; ++i) dst[i * 256 + t] = srcT[i * 256 + t];
}

// ---------------------------------------------------------------------------
// Kernel 2: normalize x rows -> x_n (written straight into d_out region 2)
// ---------------------------------------------------------------------------
__global__ __launch_bounds__(256) void k_x(const float* __restrict__ xin,
                                           float* __restrict__ xn) {
    const int t = threadIdx.x;
    const int wv = t >> 6, lane = t & 63;
    const int row = blockIdx.x * 4 + wv;
    float v = xin[row * D + lane];
    float ss = v * v;
    #pragma unroll
    for (int off = 32; off; off >>= 1) ss += __shfl_xor(ss, off, 64);
    const float n = sqrtf(ss);
    xn[row * D + lane] = v / (n + EPSV);
}

// ---------------------------------------------------------------------------
// Kernel 3: fused  -x_n·cb_n^T  +  mask-fill  +  row argmin  +  gather/outputs
//   block = 256 threads (4 waves), 32 rows/block (8 rows/wave), lanes <-> codes
// ---------------------------------------------------------------------------
__global__ __launch_bounds__(256) void k_main(const float* __restrict__ xn,
                                              const float4* __restrict__ cbt,
                                              const float* __restrict__ cb,
                                              const int* __restrict__ mask,
                                              const int* __restrict__ training,
                                              float* __restrict__ out,
                                              int B, int K) {
    __shared__ float4 cbs[1024];     // [g][c] 16 KB
    __shared__ float4 xs[32 * 16];   // [row][g] 8 KB
    const int t = threadIdx.x;
    const int wv = t >> 6, lane = t & 63;
    const int row0 = blockIdx.x * 32;
    const int tr = training[0];

    // stage this block's 32 x_n rows once
    const float4* x4 = (const float4*)xn + (size_t)row0 * 16;
    xs[t] = x4[t];
    xs[256 + t] = x4[256 + t];

    float best[8];
    int bidx[8];
    #pragma unroll
    for (int r = 0; r < 8; ++r) { best[r] = FLT_MAX; bidx[r] = 0; }

    const int nTiles = K / 64;
    for (int tk = 0; tk < nTiles; ++tk) {
        const float4* src = cbt + (size_t)tk * 1024;
        #pragma unroll
        for (int i = 0; i < 4; ++i) cbs[i * 256 + t] = src[i * 256 + t];
        __syncthreads();

        float4 cv[16];
        #pragma unroll
        for (int g = 0; g < 16; ++g) cv[g] = cbs[g * 64 + lane];

        const int k = tk * 64 + lane;
        #pragma unroll
        for (int r = 0; r < 8; ++r) {
            const int lrow = wv * 8 + r;
            float sim = 0.f;
            #pragma unroll
            for (int g = 0; g < 16; ++g) {
                const float4 xv = xs[lrow * 16 + g];
                sim += xv.x * cv[g].x + xv.y * cv[g].y +
                       xv.z * cv[g].z + xv.w * cv[g].w;
            }
            const int m = mask[(long long)(row0 + lrow) * K + k];
            const float dist = (m != 0 || tr == 0) ? -sim : MASK_FILL;
            if (dist < best[r]) { best[r] = dist; bidx[r] = k; }  // first-min kept
        }
        __syncthreads();
    }

    float* out_zq  = out;
    float* out_z   = out + (size_t)B * D;
    float* out_idx = out + (size_t)3 * B * D;
    const float* xsf = (const float*)xs;

    #pragma unroll
    for (int r = 0; r < 8; ++r) {
        const int lrow = wv * 8 + r;
        float b = best[r];
        int bi = bidx[r];
        #pragma unroll
        for (int off = 32; off; off >>= 1) {
            const float ob = __shfl_xor(b, off, 64);
            const int   oi = __shfl_xor(bi, off, 64);
            if (ob < b || (ob == b && oi < bi)) { b = ob; bi = oi; }
        }
        const int grow = row0 + lrow;
        const float zv  = cb[(size_t)bi * D + lane];
        const float xnv = xsf[lrow * 64 + lane];
        const float zq  = xnv + (zv - xnv);   // literal straight-through math
        out_zq[(size_t)grow * D + lane] = zq;
        out_z [(size_t)grow * D + lane] = zv;
        if (lane == 0) out_idx[grow] = (float)bi;
    }
}

extern "C" void kernel_launch(void* const* d_in, const int* in_sizes, int n_in,
                              void* d_out, int out_size, void* d_ws, size_t ws_size,
                              hipStream_t stream) {
    const float* x    = (const float*)d_in[0];
    const float* cbin = (const float*)d_in[1];
    const int* mask   = (const int*)d_in[2];
    const int* train  = (const int*)d_in[3];
    const int B = in_sizes[0] / D;   // 16384
    const int K = in_sizes[1] / D;   // 16384
    float* out = (float*)d_out;

    float*  cb  = (float*)d_ws;                                   // K*64 f32 = 4 MB
    float4* cbt = (float4*)((char*)d_ws + (size_t)K * D * 4);     // 4 MB, tiled-transposed

    float* out_xn = out + (size_t)2 * B * D;

    k_cb  <<<K / 64, 256, 0, stream>>>(cbin, cb, cbt);
    k_x   <<<B / 4,  256, 0, stream>>>(x, out_xn);
    k_main<<<B / 32, 256, 0, stream>>>(out_xn, cbt, cb, mask, train, out, B, K);
}